// Round 1
// baseline (896.305 us; speedup 1.0000x reference)
//
#include <hip/hip_runtime.h>

#define NN   100000
#define NE   3200000
#define DIMK 512
#define HIDN 16
#define NCLS 64
#define NB   98          // scan blocks: 98 * 1024 >= NN

// ---- threefry2x32-20, JAX partitionable 32-bit path: bits = x0_final ^ x1_final,
// key=(0,42), counter=(0, i). Verified R3 (absmax 0.031).
__device__ __forceinline__ unsigned rotl32(unsigned x, int r){ return (x << r) | (x >> (32 - r)); }

__device__ __forceinline__ unsigned threefry_bits(unsigned i){
  const unsigned k0 = 0u, k1 = 42u;
  const unsigned k2 = 0x1BD11BDAu ^ k0 ^ k1;
  unsigned a = 0u + k0, b = i + k1;
#define TF_R(r) { a += b; b = rotl32(b, (r)); b ^= a; }
  TF_R(13) TF_R(15) TF_R(26) TF_R(6)  a += k1; b += k2 + 1u;
  TF_R(17) TF_R(29) TF_R(16) TF_R(24) a += k2; b += k0 + 2u;
  TF_R(13) TF_R(15) TF_R(26) TF_R(6)  a += k0; b += k1 + 3u;
  TF_R(17) TF_R(29) TF_R(16) TF_R(24) a += k1; b += k2 + 4u;
  TF_R(13) TF_R(15) TF_R(26) TF_R(6)  a += k2; b += k0 + 5u;
#undef TF_R
  return a ^ b;   // keep iff !(bits & 0x80000000)
}

// ---------------- degree count ----------------
__global__ void k_count(const int* __restrict__ col, int* __restrict__ cnt){
  int e = blockIdx.x * blockDim.x + threadIdx.x;
  if (e < NE) atomicAdd(&cnt[col[e]], 1);
}

// ---------------- prefix sum over degree counts (3 tiny kernels) ----------------
// scan1: per-block (1024-wide) exclusive scan -> offs, block totals -> bsum
__global__ __launch_bounds__(1024) void k_scan1(const int* __restrict__ cnt,
                                                int* __restrict__ offs,
                                                int* __restrict__ bsum){
  __shared__ int sh[1024];
  const int tid = threadIdx.x;
  const int g = blockIdx.x * 1024 + tid;
  int v = (g < NN) ? cnt[g] : 0;
  int x = v;
  sh[tid] = x; __syncthreads();
  for (int d = 1; d < 1024; d <<= 1){
    int y = (tid >= d) ? sh[tid - d] : 0;
    __syncthreads();
    x += y;
    sh[tid] = x;
    __syncthreads();
  }
  if (g < NN) offs[g] = x - v;            // exclusive within block
  if (tid == 1023) bsum[blockIdx.x] = x;  // block total
}

// scan2: serial exclusive scan of 98 block totals (trivial)
__global__ void k_scan2(int* __restrict__ bsum){
  if (threadIdx.x == 0 && blockIdx.x == 0){
    int acc = 0;
    for (int b = 0; b < NB; ++b){ int t = bsum[b]; bsum[b] = acc; acc += t; }
  }
}

// scan3: add block offsets -> global exclusive scan; also compute dis
__global__ void k_scan3(int* __restrict__ offs, const int* __restrict__ bsum,
                        const int* __restrict__ cnt, float* __restrict__ dis){
  int g = blockIdx.x * blockDim.x + threadIdx.x;
  if (g < NN){
    offs[g] += bsum[g >> 10];
    dis[g] = rsqrtf((float)(cnt[g] + 1));   // +1 self-loop; deg >= 1 always
  }
}

// ---------------- CSR build: bin sources by destination ----------------
// atomicAdd on offs itself: after this kernel offs[c] == END pointer of c's list;
// start = offs[c] - cnt[c]. 3.2M int atomics (vs 51.2M f32 per scat before).
__global__ void k_build(const int* __restrict__ row, const int* __restrict__ col,
                        int* __restrict__ offs, int* __restrict__ csr){
  int e = blockIdx.x * blockDim.x + threadIdx.x;
  if (e < NE){
    int c = col[e];
    int p = atomicAdd(&offs[c], 1);
    csr[p] = row[e];
  }
}

// ---- h1 = x @ W1, epilogue pre-scales by dis[n]: hs = h1 * dis[n] ----
__global__ __launch_bounds__(256) void k_gemm1(const float* __restrict__ x,
                                               const float* __restrict__ W1,
                                               const float* __restrict__ dis,
                                               float* __restrict__ hs){
  const int lane = threadIdx.x & 63;
  const int wid  = (blockIdx.x * blockDim.x + threadIdx.x) >> 6;
  const int nw   = (gridDim.x * blockDim.x) >> 6;
  const bool s5 = (lane & 32) != 0;
  const bool s4 = (lane & 16) != 0;
  const bool s3 = (lane & 8)  != 0;
  const bool s2 = (lane & 4)  != 0;

  // lane holds W1 rows [lane*8, lane*8+8), all 16 cols -> 128 VGPRs
  float4 w4[8][4];
  const float4* W1v = (const float4*)W1;
#pragma unroll
  for (int k = 0; k < 8; ++k)
#pragma unroll
    for (int jj = 0; jj < 4; ++jj)
      w4[k][jj] = W1v[(lane * 8 + k) * 4 + jj];

  for (int n = wid; n < NN; n += nw){
    const float4* xp = (const float4*)(x + (size_t)n * DIMK + lane * 8);
    float4 xa = xp[0], xb = xp[1];
    float xv[8] = {xa.x, xa.y, xa.z, xa.w, xb.x, xb.y, xb.z, xb.w};
    float acc[16];
#pragma unroll
    for (int j = 0; j < 16; ++j) acc[j] = 0.f;
#pragma unroll
    for (int k = 0; k < 8; ++k){
      float xk = xv[k];
#pragma unroll
      for (int jj = 0; jj < 4; ++jj){
        acc[jj*4+0] = fmaf(xk, w4[k][jj].x, acc[jj*4+0]);
        acc[jj*4+1] = fmaf(xk, w4[k][jj].y, acc[jj*4+1]);
        acc[jj*4+2] = fmaf(xk, w4[k][jj].z, acc[jj*4+2]);
        acc[jj*4+3] = fmaf(xk, w4[k][jj].w, acc[jj*4+3]);
      }
    }
    // value-folding reduction: 16 partials x 64 lanes
    float t8[8];
#pragma unroll
    for (int m = 0; m < 8; ++m){
      float keep = s5 ? acc[8+m] : acc[m];
      float give = s5 ? acc[m]   : acc[8+m];
      t8[m] = keep + __shfl_xor(give, 32, 64);
    }
    float t4[4];
#pragma unroll
    for (int m = 0; m < 4; ++m){
      float keep = s4 ? t8[4+m] : t8[m];
      float give = s4 ? t8[m]   : t8[4+m];
      t4[m] = keep + __shfl_xor(give, 16, 64);
    }
    float t2[2];
#pragma unroll
    for (int m = 0; m < 2; ++m){
      float keep = s3 ? t4[2+m] : t4[m];
      float give = s3 ? t4[m]   : t4[2+m];
      t2[m] = keep + __shfl_xor(give, 8, 64);
    }
    float keep = s2 ? t2[1] : t2[0];
    float give = s2 ? t2[0] : t2[1];
    float v = keep + __shfl_xor(give, 4, 64);
    v += __shfl_xor(v, 2, 64);
    v += __shfl_xor(v, 1, 64);
    float hv = __shfl(v, (lane & 15) * 4, 64);
    if (lane < 16) hs[(size_t)n * HIDN + lane] = hv * dis[n];
  }
}

// ---- layer-1 pull aggregation + fin1 fused: wave per node, atomic-free ----
// acc_j = sum over in-edges of hs[r*16+j]; v = dis*(acc + hs[self]) + b1;
// relu -> dropout -> pre-scale by dis for layer 2.
__global__ __launch_bounds__(256) void k_agg1(const int* __restrict__ csr,
                                              const int* __restrict__ offs_end,
                                              const int* __restrict__ degc,
                                              const float* __restrict__ hs,
                                              const float* __restrict__ dis,
                                              const float* __restrict__ b1,
                                              float* __restrict__ h2s){
  const int lane = threadIdx.x & 63;
  const int wid  = (blockIdx.x * blockDim.x + threadIdx.x) >> 6;
  const int nw   = (gridDim.x * blockDim.x) >> 6;
  const int j  = lane & 15;
  const int c4 = lane >> 4;          // 4 edge-chunks per wave
  for (int n = wid; n < NN; n += nw){
    const int end   = offs_end[n];
    const int start = end - degc[n];
    float acc = 0.f;
    for (int i = start + c4; i < end; i += 4){
      int r = csr[i];
      acc += hs[r * HIDN + j];       // 16 lanes -> one 64B line per edge
    }
    acc += __shfl_xor(acc, 16, 64);
    acc += __shfl_xor(acc, 32, 64);  // lanes with same j now hold full sum
    if (lane < 16){
      float dn = dis[n];
      int t = n * HIDN + lane;
      float v = fmaf(dn, acc + hs[t], b1[lane]);
      v = fmaxf(v, 0.f);
      unsigned bits = threefry_bits((unsigned)t);
      float kept = (bits & 0x80000000u) ? 0.f : v * 2.f;   // /(1-p) = *2
      h2s[t] = kept * dn;                                   // pre-scale for layer 2
    }
  }
}

// ---- layer-2 pull aggregation + W2 matmul + log_softmax fused: wave per node ----
__global__ __launch_bounds__(256) void k_agg2out(const int* __restrict__ csr,
                                                 const int* __restrict__ offs_end,
                                                 const int* __restrict__ degc,
                                                 const float* __restrict__ h2s,
                                                 const float* __restrict__ dis,
                                                 const float* __restrict__ W2,
                                                 const float* __restrict__ b2,
                                                 float* __restrict__ out){
  const int lane = threadIdx.x & 63;
  const int wid  = (blockIdx.x * blockDim.x + threadIdx.x) >> 6;
  const int nw   = (gridDim.x * blockDim.x) >> 6;
  const int j  = lane & 15;
  const int c4 = lane >> 4;
  float wc[16];
#pragma unroll
  for (int k = 0; k < 16; ++k) wc[k] = W2[k * NCLS + lane];
  const float bb = b2[lane];
  for (int n = wid; n < NN; n += nw){
    const int end   = offs_end[n];
    const int start = end - degc[n];
    float acc = 0.f;
    for (int i = start + c4; i < end; i += 4){
      int r = csr[i];
      acc += h2s[r * HIDN + j];
    }
    acc += __shfl_xor(acc, 16, 64);
    acc += __shfl_xor(acc, 32, 64);
    float dn = dis[n];
    float aggj = dn * (acc + h2s[n * HIDN + j]);   // lane l holds feature l&15
    float s = bb;
#pragma unroll
    for (int k = 0; k < 16; ++k) s = fmaf(__shfl(aggj, k, 64), wc[k], s);
    // log_softmax over the 64 classes (one per lane)
    float m = s;
#pragma unroll
    for (int d = 32; d; d >>= 1) m = fmaxf(m, __shfl_xor(m, d, 64));
    float ex = __expf(s - m);
    float sum = ex;
#pragma unroll
    for (int d = 32; d; d >>= 1) sum += __shfl_xor(sum, d, 64);
    out[(size_t)n * NCLS + lane] = (s - m) - __logf(sum);
  }
}

// ---------------- launch ----------------
extern "C" void kernel_launch(void* const* d_in, const int* in_sizes, int n_in,
                              void* d_out, int out_size, void* d_ws, size_t ws_size,
                              hipStream_t stream){
  const float* x  = (const float*)d_in[0];
  const int*   ei = (const int*)  d_in[1];
  const float* W1 = (const float*)d_in[2];
  const float* b1 = (const float*)d_in[3];
  const float* W2 = (const float*)d_in[4];
  const float* b2 = (const float*)d_in[5];
  float* out = (float*)d_out;
  const int* row = ei;          // sources
  const int* col = ei + NE;     // destinations

  char* ws = (char*)d_ws;
  int*   degcnt = (int*)  (ws + 0);           // 400 KB  (edge-only in-degree)
  int*   offs   = (int*)  (ws + 400000);      // 400 KB  (excl scan -> end ptrs after build)
  float* dis    = (float*)(ws + 800000);      // 400 KB
  int*   bsum   = (int*)  (ws + 1200000);     // ~4 KB   (scan block totals)
  int*   csr    = (int*)  (ws + 1204000);     // 12.8 MB (sources binned by destination)
  float* hs     = (float*)(ws + 14004000);    // 6.4 MB  (h1 * dis)
  float* h2s    = (float*)(ws + 20404000);    // 6.4 MB  (dropout(relu(l1)) * dis)

  hipMemsetAsync(degcnt, 0, NN * sizeof(int), stream);
  k_count <<<(NE + 255) / 256, 256, 0, stream>>>(col, degcnt);
  k_scan1 <<<NB, 1024, 0, stream>>>(degcnt, offs, bsum);
  k_scan2 <<<1, 64, 0, stream>>>(bsum);
  k_scan3 <<<(NN + 255) / 256, 256, 0, stream>>>(offs, bsum, degcnt, dis);
  k_gemm1 <<<1024, 256, 0, stream>>>(x, W1, dis, hs);
  k_build <<<(NE + 255) / 256, 256, 0, stream>>>(row, col, offs, csr);
  k_agg1  <<<2048, 256, 0, stream>>>(csr, offs, degcnt, hs, dis, b1, h2s);
  k_agg2out<<<2048, 256, 0, stream>>>(csr, offs, degcnt, h2s, dis, W2, b2, out);
}

// Round 2
// 619.560 us; speedup vs baseline: 1.4467x; 1.4467x over previous
//
#include <hip/hip_runtime.h>

#define NN    100000
#define NE    3200000
#define DIMK  512
#define HIDN  16
#define NCLS  64
#define NBUCK 391        // ceil(NN / 256) coarse buckets (dest >> 8)
#define NBLK  512        // coarse-pass chunks
#define CHUNK 6250       // NE / NBLK exactly

// ---- threefry2x32-20, JAX partitionable 32-bit path: bits = x0_final ^ x1_final,
// key=(0,42), counter=(0, i). Verified (absmax 0.031).
__device__ __forceinline__ unsigned rotl32(unsigned x, int r){ return (x << r) | (x >> (32 - r)); }

__device__ __forceinline__ unsigned threefry_bits(unsigned i){
  const unsigned k0 = 0u, k1 = 42u;
  const unsigned k2 = 0x1BD11BDAu ^ k0 ^ k1;
  unsigned a = 0u + k0, b = i + k1;
#define TF_R(r) { a += b; b = rotl32(b, (r)); b ^= a; }
  TF_R(13) TF_R(15) TF_R(26) TF_R(6)  a += k1; b += k2 + 1u;
  TF_R(17) TF_R(29) TF_R(16) TF_R(24) a += k2; b += k0 + 2u;
  TF_R(13) TF_R(15) TF_R(26) TF_R(6)  a += k0; b += k1 + 3u;
  TF_R(17) TF_R(29) TF_R(16) TF_R(24) a += k1; b += k2 + 4u;
  TF_R(13) TF_R(15) TF_R(26) TF_R(6)  a += k2; b += k0 + 5u;
#undef TF_R
  return a ^ b;   // keep iff !(bits & 0x80000000)
}

// ---------------- CSR build: deterministic two-level counting sort ----------------
// kp1: coarse histogram per chunk -> M[blk*NBUCK + b]  (LDS atomics only)
__global__ __launch_bounds__(256) void kp1_hist(const int* __restrict__ col, int* __restrict__ M){
  __shared__ int h[NBUCK];
  const int blk = blockIdx.x, t = threadIdx.x;
  for (int q = t; q < NBUCK; q += 256) h[q] = 0;
  __syncthreads();
  const int e0 = blk * CHUNK;
  for (int i = t; i < CHUNK; i += 256)
    atomicAdd(&h[col[e0 + i] >> 8], 1);
  __syncthreads();
  for (int q = t; q < NBUCK; q += 256) M[blk * NBUCK + q] = h[q];
}

// kp2: per-bucket exclusive scan across chunks (in place); bucket totals -> btot
__global__ __launch_bounds__(256) void kp2_rowscan(int* __restrict__ M, int* __restrict__ btot){
  int b = blockIdx.x * 256 + threadIdx.x;
  if (b >= NBUCK) return;
  int acc = 0;
  for (int blk = 0; blk < NBLK; ++blk){
    int idx = blk * NBUCK + b;
    int v = M[idx];
    M[idx] = acc;
    acc += v;
  }
  btot[b] = acc;
}

// kp2b: exclusive scan of bucket totals -> bbase[NBUCK+1]
__global__ __launch_bounds__(512) void kp2b_bscan(const int* __restrict__ btot, int* __restrict__ bbase){
  __shared__ int s[512];
  const int t = threadIdx.x;
  int v = (t < NBUCK) ? btot[t] : 0;
  int x = v;
  s[t] = x; __syncthreads();
  for (int d = 1; d < 512; d <<= 1){
    int y = (t >= d) ? s[t - d] : 0;
    __syncthreads();
    x += y; s[t] = x;
    __syncthreads();
  }
  if (t < NBUCK) bbase[t] = x - v;
  if (t == NBUCK - 1) bbase[NBUCK] = x;   // == NE
}

// kp3: coarse scatter, packed (c&255)<<17 | src (src < 2^17). Each (bucket,chunk)
// segment written by exactly one block -> lines single-XCD-owned -> L2 write-merge.
__global__ __launch_bounds__(256) void kp3_scatter(const int* __restrict__ row, const int* __restrict__ col,
                                                   const int* __restrict__ M, const int* __restrict__ bbase,
                                                   unsigned* __restrict__ coarse){
  __shared__ int cur[NBUCK];
  const int blk = blockIdx.x, t = threadIdx.x;
  for (int q = t; q < NBUCK; q += 256) cur[q] = bbase[q] + M[blk * NBUCK + q];
  __syncthreads();
  const int e0 = blk * CHUNK;
  for (int i = t; i < CHUNK; i += 256){
    int c = col[e0 + i];
    int r = row[e0 + i];
    int p = atomicAdd(&cur[c >> 8], 1);            // LDS atomic
    coarse[p] = ((unsigned)(c & 255) << 17) | (unsigned)r;
  }
}

// kp4: one block per bucket: fine sort within block-exclusive csr region; emits
// per-dest start/count/dis (replaces k_count + global scan entirely).
__global__ __launch_bounds__(256) void kp4_fine(const unsigned* __restrict__ coarse,
                                                const int* __restrict__ bbase,
                                                int* __restrict__ csr,
                                                int* __restrict__ dstart,
                                                int* __restrict__ dcnt,
                                                float* __restrict__ dis){
  __shared__ int cnt[256], ofs[256], rk[256], s[256];
  const int b = blockIdx.x, t = threadIdx.x;
  const int base = bbase[b];
  const int nreg = bbase[b + 1] - base;
  cnt[t] = 0; rk[t] = 0;
  __syncthreads();
  for (int i = t; i < nreg; i += 256)
    atomicAdd(&cnt[coarse[base + i] >> 17], 1);
  __syncthreads();
  const int deg = cnt[t];
  int x = deg;
  s[t] = x; __syncthreads();
  for (int d = 1; d < 256; d <<= 1){
    int y = (t >= d) ? s[t - d] : 0;
    __syncthreads();
    x += y; s[t] = x;
    __syncthreads();
  }
  ofs[t] = x - deg;
  __syncthreads();
  const int n = (b << 8) + t;
  if (n < NN){
    dstart[n] = base + ofs[t];
    dcnt[n]   = deg;
    dis[n]    = rsqrtf((float)(deg + 1));   // +1 self-loop
  }
  for (int i = t; i < nreg; i += 256){
    unsigned p = coarse[base + i];
    int l = p >> 17;
    int r = atomicAdd(&rk[l], 1);           // LDS atomic
    csr[base + ofs[l] + r] = (int)(p & 0x1FFFFu);
  }
}

// ---- h1 = x @ W1, epilogue pre-scales by dis[n]: hs = h1 * dis[n] ----
__global__ __launch_bounds__(256) void k_gemm1(const float* __restrict__ x,
                                               const float* __restrict__ W1,
                                               const float* __restrict__ dis,
                                               float* __restrict__ hs){
  const int lane = threadIdx.x & 63;
  const int wid  = (blockIdx.x * blockDim.x + threadIdx.x) >> 6;
  const int nw   = (gridDim.x * blockDim.x) >> 6;
  const bool s5 = (lane & 32) != 0;
  const bool s4 = (lane & 16) != 0;
  const bool s3 = (lane & 8)  != 0;
  const bool s2 = (lane & 4)  != 0;

  float4 w4[8][4];
  const float4* W1v = (const float4*)W1;
#pragma unroll
  for (int k = 0; k < 8; ++k)
#pragma unroll
    for (int jj = 0; jj < 4; ++jj)
      w4[k][jj] = W1v[(lane * 8 + k) * 4 + jj];

  for (int n = wid; n < NN; n += nw){
    const float4* xp = (const float4*)(x + (size_t)n * DIMK + lane * 8);
    float4 xa = xp[0], xb = xp[1];
    float xv[8] = {xa.x, xa.y, xa.z, xa.w, xb.x, xb.y, xb.z, xb.w};
    float acc[16];
#pragma unroll
    for (int j = 0; j < 16; ++j) acc[j] = 0.f;
#pragma unroll
    for (int k = 0; k < 8; ++k){
      float xk = xv[k];
#pragma unroll
      for (int jj = 0; jj < 4; ++jj){
        acc[jj*4+0] = fmaf(xk, w4[k][jj].x, acc[jj*4+0]);
        acc[jj*4+1] = fmaf(xk, w4[k][jj].y, acc[jj*4+1]);
        acc[jj*4+2] = fmaf(xk, w4[k][jj].z, acc[jj*4+2]);
        acc[jj*4+3] = fmaf(xk, w4[k][jj].w, acc[jj*4+3]);
      }
    }
    float t8[8];
#pragma unroll
    for (int m = 0; m < 8; ++m){
      float keep = s5 ? acc[8+m] : acc[m];
      float give = s5 ? acc[m]   : acc[8+m];
      t8[m] = keep + __shfl_xor(give, 32, 64);
    }
    float t4[4];
#pragma unroll
    for (int m = 0; m < 4; ++m){
      float keep = s4 ? t8[4+m] : t8[m];
      float give = s4 ? t8[m]   : t8[4+m];
      t4[m] = keep + __shfl_xor(give, 16, 64);
    }
    float t2[2];
#pragma unroll
    for (int m = 0; m < 2; ++m){
      float keep = s3 ? t4[2+m] : t4[m];
      float give = s3 ? t4[m]   : t4[2+m];
      t2[m] = keep + __shfl_xor(give, 8, 64);
    }
    float keep = s2 ? t2[1] : t2[0];
    float give = s2 ? t2[0] : t2[1];
    float v = keep + __shfl_xor(give, 4, 64);
    v += __shfl_xor(v, 2, 64);
    v += __shfl_xor(v, 1, 64);
    float hv = __shfl(v, (lane & 15) * 4, 64);
    if (lane < 16) hs[(size_t)n * HIDN + lane] = hv * dis[n];
  }
}

// ---- layer-1 pull aggregation + fin1 fused: wave per node, atomic-free ----
__global__ __launch_bounds__(256) void k_agg1(const int* __restrict__ csr,
                                              const int* __restrict__ dstart,
                                              const int* __restrict__ dcnt,
                                              const float* __restrict__ hs,
                                              const float* __restrict__ dis,
                                              const float* __restrict__ b1,
                                              float* __restrict__ h2s){
  const int lane = threadIdx.x & 63;
  const int wid  = (blockIdx.x * blockDim.x + threadIdx.x) >> 6;
  const int nw   = (gridDim.x * blockDim.x) >> 6;
  const int j  = lane & 15;
  const int c4 = lane >> 4;
  for (int n = wid; n < NN; n += nw){
    const int start = dstart[n];
    const int end   = start + dcnt[n];
    float acc = 0.f;
    for (int i = start + c4; i < end; i += 4){
      int r = csr[i];
      acc += hs[r * HIDN + j];
    }
    acc += __shfl_xor(acc, 16, 64);
    acc += __shfl_xor(acc, 32, 64);
    if (lane < 16){
      float dn = dis[n];
      int t = n * HIDN + lane;
      float v = fmaf(dn, acc + hs[t], b1[lane]);
      v = fmaxf(v, 0.f);
      unsigned bits = threefry_bits((unsigned)t);
      float kept = (bits & 0x80000000u) ? 0.f : v * 2.f;   // /(1-p) = *2
      h2s[t] = kept * dn;                                   // pre-scale for layer 2
    }
  }
}

// ---- layer-2 pull aggregation + W2 matmul + log_softmax fused: wave per node ----
__global__ __launch_bounds__(256) void k_agg2out(const int* __restrict__ csr,
                                                 const int* __restrict__ dstart,
                                                 const int* __restrict__ dcnt,
                                                 const float* __restrict__ h2s,
                                                 const float* __restrict__ dis,
                                                 const float* __restrict__ W2,
                                                 const float* __restrict__ b2,
                                                 float* __restrict__ out){
  const int lane = threadIdx.x & 63;
  const int wid  = (blockIdx.x * blockDim.x + threadIdx.x) >> 6;
  const int nw   = (gridDim.x * blockDim.x) >> 6;
  const int j  = lane & 15;
  const int c4 = lane >> 4;
  float wc[16];
#pragma unroll
  for (int k = 0; k < 16; ++k) wc[k] = W2[k * NCLS + lane];
  const float bb = b2[lane];
  for (int n = wid; n < NN; n += nw){
    const int start = dstart[n];
    const int end   = start + dcnt[n];
    float acc = 0.f;
    for (int i = start + c4; i < end; i += 4){
      int r = csr[i];
      acc += h2s[r * HIDN + j];
    }
    acc += __shfl_xor(acc, 16, 64);
    acc += __shfl_xor(acc, 32, 64);
    float dn = dis[n];
    float aggj = dn * (acc + h2s[n * HIDN + j]);
    float s = bb;
#pragma unroll
    for (int k = 0; k < 16; ++k) s = fmaf(__shfl(aggj, k, 64), wc[k], s);
    float m = s;
#pragma unroll
    for (int d = 32; d; d >>= 1) m = fmaxf(m, __shfl_xor(m, d, 64));
    float ex = __expf(s - m);
    float sum = ex;
#pragma unroll
    for (int d = 32; d; d >>= 1) sum += __shfl_xor(sum, d, 64);
    out[(size_t)n * NCLS + lane] = (s - m) - __logf(sum);
  }
}

// ---------------- launch ----------------
extern "C" void kernel_launch(void* const* d_in, const int* in_sizes, int n_in,
                              void* d_out, int out_size, void* d_ws, size_t ws_size,
                              hipStream_t stream){
  const float* x  = (const float*)d_in[0];
  const int*   ei = (const int*)  d_in[1];
  const float* W1 = (const float*)d_in[2];
  const float* b1 = (const float*)d_in[3];
  const float* W2 = (const float*)d_in[4];
  const float* b2 = (const float*)d_in[5];
  float* out = (float*)d_out;
  const int* row = ei;          // sources
  const int* col = ei + NE;     // destinations

  char* ws = (char*)d_ws;
  int*      M      = (int*)     (ws + 0);          // 800,768 B  coarse matrix
  int*      btot   = (int*)     (ws + 800768);     // 1.6 KB
  int*      bbase  = (int*)     (ws + 802368);     // 1.6 KB
  int*      dstart = (int*)     (ws + 803968);     // 400 KB
  int*      dcnt   = (int*)     (ws + 1203968);    // 400 KB
  float*    dis    = (float*)   (ws + 1603968);    // 400 KB
  int*      csr    = (int*)     (ws + 2003968);    // 12.8 MB
  unsigned* coarse = (unsigned*)(ws + 14803968);   // 12.8 MB (dead after kp4)
  float*    hs     = (float*)   (ws + 14803968);   // 6.4 MB  (aliases coarse)
  float*    h2s    = (float*)   (ws + 21203968);   // 6.4 MB  (aliases coarse hi half)

  kp1_hist   <<<NBLK, 256, 0, stream>>>(col, M);
  kp2_rowscan<<<2, 256, 0, stream>>>(M, btot);
  kp2b_bscan <<<1, 512, 0, stream>>>(btot, bbase);
  kp3_scatter<<<NBLK, 256, 0, stream>>>(row, col, M, bbase, coarse);
  kp4_fine   <<<NBUCK, 256, 0, stream>>>(coarse, bbase, csr, dstart, dcnt, dis);
  k_gemm1    <<<1024, 256, 0, stream>>>(x, W1, dis, hs);
  k_agg1     <<<2048, 256, 0, stream>>>(csr, dstart, dcnt, hs, dis, b1, h2s);
  k_agg2out  <<<2048, 256, 0, stream>>>(csr, dstart, dcnt, h2s, dis, W2, b2, out);
}

// Round 3
// 598.780 us; speedup vs baseline: 1.4969x; 1.0347x over previous
//
#include <hip/hip_runtime.h>

#define NN    100000
#define NE    3200000
#define DIMK  512
#define HIDN  16
#define NCLS  64
#define NBUCK 391        // ceil(NN / 256) coarse buckets (dest >> 8)
#define NBLK  512        // coarse-pass chunks
#define CHUNK 6250       // NE / NBLK exactly

// ---- threefry2x32-20, JAX partitionable 32-bit path: bits = x0_final ^ x1_final,
// key=(0,42), counter=(0, i). Verified (absmax 0.031).
__device__ __forceinline__ unsigned rotl32(unsigned x, int r){ return (x << r) | (x >> (32 - r)); }

__device__ __forceinline__ unsigned threefry_bits(unsigned i){
  const unsigned k0 = 0u, k1 = 42u;
  const unsigned k2 = 0x1BD11BDAu ^ k0 ^ k1;
  unsigned a = 0u + k0, b = i + k1;
#define TF_R(r) { a += b; b = rotl32(b, (r)); b ^= a; }
  TF_R(13) TF_R(15) TF_R(26) TF_R(6)  a += k1; b += k2 + 1u;
  TF_R(17) TF_R(29) TF_R(16) TF_R(24) a += k2; b += k0 + 2u;
  TF_R(13) TF_R(15) TF_R(26) TF_R(6)  a += k0; b += k1 + 3u;
  TF_R(17) TF_R(29) TF_R(16) TF_R(24) a += k1; b += k2 + 4u;
  TF_R(13) TF_R(15) TF_R(26) TF_R(6)  a += k2; b += k0 + 5u;
#undef TF_R
  return a ^ b;   // keep iff !(bits & 0x80000000)
}

// ---------------- CSR build: deterministic two-level counting sort ----------------
// kp1: coarse histogram per chunk -> M[blk*NBUCK + b]  (LDS atomics only)
__global__ __launch_bounds__(256) void kp1_hist(const int* __restrict__ col, int* __restrict__ M){
  __shared__ int h[NBUCK];
  const int blk = blockIdx.x, t = threadIdx.x;
  for (int q = t; q < NBUCK; q += 256) h[q] = 0;
  __syncthreads();
  const int e0 = blk * CHUNK;
  for (int i = t; i < CHUNK; i += 256)
    atomicAdd(&h[col[e0 + i] >> 8], 1);
  __syncthreads();
  for (int q = t; q < NBUCK; q += 256) M[blk * NBUCK + q] = h[q];
}

// kp2: per-bucket exclusive scan across chunks, PARALLEL: one block per bucket,
// one thread per chunk. (Old version: 391 threads total, 512-deep serial
// dependent load/store chain -> ~latency-bound whale. This is 391 blocks.)
__global__ __launch_bounds__(512) void kp2_rowscan(int* __restrict__ M, int* __restrict__ btot){
  __shared__ int s[512];
  const int b = blockIdx.x, t = threadIdx.x;     // b < NBUCK, t < NBLK
  const int idx = t * NBUCK + b;
  int v = M[idx];
  int x = v;
  s[t] = x; __syncthreads();
  for (int d = 1; d < 512; d <<= 1){
    int y = (t >= d) ? s[t - d] : 0;
    __syncthreads();
    x += y; s[t] = x;
    __syncthreads();
  }
  M[idx] = x - v;                 // exclusive over chunks
  if (t == 511) btot[b] = x;      // bucket total
}

// kp2b: exclusive scan of bucket totals -> bbase[NBUCK+1]
__global__ __launch_bounds__(512) void kp2b_bscan(const int* __restrict__ btot, int* __restrict__ bbase){
  __shared__ int s[512];
  const int t = threadIdx.x;
  int v = (t < NBUCK) ? btot[t] : 0;
  int x = v;
  s[t] = x; __syncthreads();
  for (int d = 1; d < 512; d <<= 1){
    int y = (t >= d) ? s[t - d] : 0;
    __syncthreads();
    x += y; s[t] = x;
    __syncthreads();
  }
  if (t < NBUCK) bbase[t] = x - v;
  if (t == NBUCK - 1) bbase[NBUCK] = x;   // == NE
}

// kp3: coarse scatter, packed (c&255)<<17 | src (src < 2^17). Each (bucket,chunk)
// segment written by exactly one block -> lines single-XCD-owned -> L2 write-merge.
__global__ __launch_bounds__(256) void kp3_scatter(const int* __restrict__ row, const int* __restrict__ col,
                                                   const int* __restrict__ M, const int* __restrict__ bbase,
                                                   unsigned* __restrict__ coarse){
  __shared__ int cur[NBUCK];
  const int blk = blockIdx.x, t = threadIdx.x;
  for (int q = t; q < NBUCK; q += 256) cur[q] = bbase[q] + M[blk * NBUCK + q];
  __syncthreads();
  const int e0 = blk * CHUNK;
  for (int i = t; i < CHUNK; i += 256){
    int c = col[e0 + i];
    int r = row[e0 + i];
    int p = atomicAdd(&cur[c >> 8], 1);            // LDS atomic
    coarse[p] = ((unsigned)(c & 255) << 17) | (unsigned)r;
  }
}

// kp4: one block per bucket: fine sort within block-exclusive csr region; emits
// per-dest start/count/dis.
__global__ __launch_bounds__(256) void kp4_fine(const unsigned* __restrict__ coarse,
                                                const int* __restrict__ bbase,
                                                int* __restrict__ csr,
                                                int* __restrict__ dstart,
                                                int* __restrict__ dcnt,
                                                float* __restrict__ dis){
  __shared__ int cnt[256], ofs[256], rk[256], s[256];
  const int b = blockIdx.x, t = threadIdx.x;
  const int base = bbase[b];
  const int nreg = bbase[b + 1] - base;
  cnt[t] = 0; rk[t] = 0;
  __syncthreads();
  for (int i = t; i < nreg; i += 256)
    atomicAdd(&cnt[coarse[base + i] >> 17], 1);
  __syncthreads();
  const int deg = cnt[t];
  int x = deg;
  s[t] = x; __syncthreads();
  for (int d = 1; d < 256; d <<= 1){
    int y = (t >= d) ? s[t - d] : 0;
    __syncthreads();
    x += y; s[t] = x;
    __syncthreads();
  }
  ofs[t] = x - deg;
  __syncthreads();
  const int n = (b << 8) + t;
  if (n < NN){
    dstart[n] = base + ofs[t];
    dcnt[n]   = deg;
    dis[n]    = rsqrtf((float)(deg + 1));   // +1 self-loop
  }
  for (int i = t; i < nreg; i += 256){
    unsigned p = coarse[base + i];
    int l = p >> 17;
    int r = atomicAdd(&rk[l], 1);           // LDS atomic
    csr[base + ofs[l] + r] = (int)(p & 0x1FFFFu);
  }
}

// ---- h1 = x @ W1, epilogue pre-scales by dis[n]: hs = h1 * dis[n] ----
__global__ __launch_bounds__(256) void k_gemm1(const float* __restrict__ x,
                                               const float* __restrict__ W1,
                                               const float* __restrict__ dis,
                                               float* __restrict__ hs){
  const int lane = threadIdx.x & 63;
  const int wid  = (blockIdx.x * blockDim.x + threadIdx.x) >> 6;
  const int nw   = (gridDim.x * blockDim.x) >> 6;
  const bool s5 = (lane & 32) != 0;
  const bool s4 = (lane & 16) != 0;
  const bool s3 = (lane & 8)  != 0;
  const bool s2 = (lane & 4)  != 0;

  float4 w4[8][4];
  const float4* W1v = (const float4*)W1;
#pragma unroll
  for (int k = 0; k < 8; ++k)
#pragma unroll
    for (int jj = 0; jj < 4; ++jj)
      w4[k][jj] = W1v[(lane * 8 + k) * 4 + jj];

  for (int n = wid; n < NN; n += nw){
    const float4* xp = (const float4*)(x + (size_t)n * DIMK + lane * 8);
    float4 xa = xp[0], xb = xp[1];
    float xv[8] = {xa.x, xa.y, xa.z, xa.w, xb.x, xb.y, xb.z, xb.w};
    float acc[16];
#pragma unroll
    for (int j = 0; j < 16; ++j) acc[j] = 0.f;
#pragma unroll
    for (int k = 0; k < 8; ++k){
      float xk = xv[k];
#pragma unroll
      for (int jj = 0; jj < 4; ++jj){
        acc[jj*4+0] = fmaf(xk, w4[k][jj].x, acc[jj*4+0]);
        acc[jj*4+1] = fmaf(xk, w4[k][jj].y, acc[jj*4+1]);
        acc[jj*4+2] = fmaf(xk, w4[k][jj].z, acc[jj*4+2]);
        acc[jj*4+3] = fmaf(xk, w4[k][jj].w, acc[jj*4+3]);
      }
    }
    float t8[8];
#pragma unroll
    for (int m = 0; m < 8; ++m){
      float keep = s5 ? acc[8+m] : acc[m];
      float give = s5 ? acc[m]   : acc[8+m];
      t8[m] = keep + __shfl_xor(give, 32, 64);
    }
    float t4[4];
#pragma unroll
    for (int m = 0; m < 4; ++m){
      float keep = s4 ? t8[4+m] : t8[m];
      float give = s4 ? t8[m]   : t8[4+m];
      t4[m] = keep + __shfl_xor(give, 16, 64);
    }
    float t2[2];
#pragma unroll
    for (int m = 0; m < 2; ++m){
      float keep = s3 ? t4[2+m] : t4[m];
      float give = s3 ? t4[m]   : t4[2+m];
      t2[m] = keep + __shfl_xor(give, 8, 64);
    }
    float keep = s2 ? t2[1] : t2[0];
    float give = s2 ? t2[0] : t2[1];
    float v = keep + __shfl_xor(give, 4, 64);
    v += __shfl_xor(v, 2, 64);
    v += __shfl_xor(v, 1, 64);
    float hv = __shfl(v, (lane & 15) * 4, 64);
    if (lane < 16) hs[(size_t)n * HIDN + lane] = hv * dis[n];
  }
}

// ---- layer-1 pull aggregation + fin1 fused: wave per node, atomic-free ----
__global__ __launch_bounds__(256) void k_agg1(const int* __restrict__ csr,
                                              const int* __restrict__ dstart,
                                              const int* __restrict__ dcnt,
                                              const float* __restrict__ hs,
                                              const float* __restrict__ dis,
                                              const float* __restrict__ b1,
                                              float* __restrict__ h2s){
  const int lane = threadIdx.x & 63;
  const int wid  = (blockIdx.x * blockDim.x + threadIdx.x) >> 6;
  const int nw   = (gridDim.x * blockDim.x) >> 6;
  const int j  = lane & 15;
  const int c4 = lane >> 4;
  for (int n = wid; n < NN; n += nw){
    const int start = dstart[n];
    const int end   = start + dcnt[n];
    float acc = 0.f;
    for (int i = start + c4; i < end; i += 4){
      int r = csr[i];
      acc += hs[r * HIDN + j];
    }
    acc += __shfl_xor(acc, 16, 64);
    acc += __shfl_xor(acc, 32, 64);
    if (lane < 16){
      float dn = dis[n];
      int t = n * HIDN + lane;
      float v = fmaf(dn, acc + hs[t], b1[lane]);
      v = fmaxf(v, 0.f);
      unsigned bits = threefry_bits((unsigned)t);
      float kept = (bits & 0x80000000u) ? 0.f : v * 2.f;   // /(1-p) = *2
      h2s[t] = kept * dn;                                   // pre-scale for layer 2
    }
  }
}

// ---- layer-2 pull aggregation + W2 matmul + log_softmax fused: wave per node ----
__global__ __launch_bounds__(256) void k_agg2out(const int* __restrict__ csr,
                                                 const int* __restrict__ dstart,
                                                 const int* __restrict__ dcnt,
                                                 const float* __restrict__ h2s,
                                                 const float* __restrict__ dis,
                                                 const float* __restrict__ W2,
                                                 const float* __restrict__ b2,
                                                 float* __restrict__ out){
  const int lane = threadIdx.x & 63;
  const int wid  = (blockIdx.x * blockDim.x + threadIdx.x) >> 6;
  const int nw   = (gridDim.x * blockDim.x) >> 6;
  const int j  = lane & 15;
  const int c4 = lane >> 4;
  float wc[16];
#pragma unroll
  for (int k = 0; k < 16; ++k) wc[k] = W2[k * NCLS + lane];
  const float bb = b2[lane];
  for (int n = wid; n < NN; n += nw){
    const int start = dstart[n];
    const int end   = start + dcnt[n];
    float acc = 0.f;
    for (int i = start + c4; i < end; i += 4){
      int r = csr[i];
      acc += h2s[r * HIDN + j];
    }
    acc += __shfl_xor(acc, 16, 64);
    acc += __shfl_xor(acc, 32, 64);
    float dn = dis[n];
    float aggj = dn * (acc + h2s[n * HIDN + j]);
    float s = bb;
#pragma unroll
    for (int k = 0; k < 16; ++k) s = fmaf(__shfl(aggj, k, 64), wc[k], s);
    float m = s;
#pragma unroll
    for (int d = 32; d; d >>= 1) m = fmaxf(m, __shfl_xor(m, d, 64));
    float ex = __expf(s - m);
    float sum = ex;
#pragma unroll
    for (int d = 32; d; d >>= 1) sum += __shfl_xor(sum, d, 64);
    out[(size_t)n * NCLS + lane] = (s - m) - __logf(sum);
  }
}

// ---------------- launch ----------------
extern "C" void kernel_launch(void* const* d_in, const int* in_sizes, int n_in,
                              void* d_out, int out_size, void* d_ws, size_t ws_size,
                              hipStream_t stream){
  const float* x  = (const float*)d_in[0];
  const int*   ei = (const int*)  d_in[1];
  const float* W1 = (const float*)d_in[2];
  const float* b1 = (const float*)d_in[3];
  const float* W2 = (const float*)d_in[4];
  const float* b2 = (const float*)d_in[5];
  float* out = (float*)d_out;
  const int* row = ei;          // sources
  const int* col = ei + NE;     // destinations

  char* ws = (char*)d_ws;
  int*      M      = (int*)     (ws + 0);          // 800,768 B  coarse matrix
  int*      btot   = (int*)     (ws + 800768);     // 1.6 KB
  int*      bbase  = (int*)     (ws + 802368);     // 1.6 KB
  int*      dstart = (int*)     (ws + 803968);     // 400 KB
  int*      dcnt   = (int*)     (ws + 1203968);    // 400 KB
  float*    dis    = (float*)   (ws + 1603968);    // 400 KB
  int*      csr    = (int*)     (ws + 2003968);    // 12.8 MB
  unsigned* coarse = (unsigned*)(ws + 14803968);   // 12.8 MB (dead after kp4)
  float*    hs     = (float*)   (ws + 14803968);   // 6.4 MB  (aliases coarse)
  float*    h2s    = (float*)   (ws + 21203968);   // 6.4 MB  (aliases coarse hi half)

  kp1_hist   <<<NBLK, 256, 0, stream>>>(col, M);
  kp2_rowscan<<<NBUCK, 512, 0, stream>>>(M, btot);
  kp2b_bscan <<<1, 512, 0, stream>>>(btot, bbase);
  kp3_scatter<<<NBLK, 256, 0, stream>>>(row, col, M, bbase, coarse);
  kp4_fine   <<<NBUCK, 256, 0, stream>>>(coarse, bbase, csr, dstart, dcnt, dis);
  k_gemm1    <<<1024, 256, 0, stream>>>(x, W1, dis, hs);
  k_agg1     <<<2048, 256, 0, stream>>>(csr, dstart, dcnt, hs, dis, b1, h2s);
  k_agg2out  <<<2048, 256, 0, stream>>>(csr, dstart, dcnt, h2s, dis, W2, b2, out);
}

// Round 4
// 564.595 us; speedup vs baseline: 1.5875x; 1.0605x over previous
//
#include <hip/hip_runtime.h>

#define NN    100000
#define NE    3200000
#define DIMK  512
#define HIDN  16
#define NCLS  64
#define NBUCK 391        // ceil(NN / 256) coarse buckets (dest >> 8)
#define NBLK  512        // coarse-pass chunks
#define CHUNK 6250       // NE / NBLK exactly

// ---- threefry2x32-20, JAX partitionable 32-bit path: bits = x0_final ^ x1_final,
// key=(0,42), counter=(0, i). Verified (absmax 0.031).
__device__ __forceinline__ unsigned rotl32(unsigned x, int r){ return (x << r) | (x >> (32 - r)); }

__device__ __forceinline__ unsigned threefry_bits(unsigned i){
  const unsigned k0 = 0u, k1 = 42u;
  const unsigned k2 = 0x1BD11BDAu ^ k0 ^ k1;
  unsigned a = 0u + k0, b = i + k1;
#define TF_R(r) { a += b; b = rotl32(b, (r)); b ^= a; }
  TF_R(13) TF_R(15) TF_R(26) TF_R(6)  a += k1; b += k2 + 1u;
  TF_R(17) TF_R(29) TF_R(16) TF_R(24) a += k2; b += k0 + 2u;
  TF_R(13) TF_R(15) TF_R(26) TF_R(6)  a += k0; b += k1 + 3u;
  TF_R(17) TF_R(29) TF_R(16) TF_R(24) a += k1; b += k2 + 4u;
  TF_R(13) TF_R(15) TF_R(26) TF_R(6)  a += k2; b += k0 + 5u;
#undef TF_R
  return a ^ b;   // keep iff !(bits & 0x80000000)
}

// ---------------- CSR build: deterministic two-level counting sort ----------------
// kp1: coarse histogram per chunk -> M[blk*NBUCK + b]  (LDS atomics only)
__global__ __launch_bounds__(256) void kp1_hist(const int* __restrict__ col, int* __restrict__ M){
  __shared__ int h[NBUCK];
  const int blk = blockIdx.x, t = threadIdx.x;
  for (int q = t; q < NBUCK; q += 256) h[q] = 0;
  __syncthreads();
  const int e0 = blk * CHUNK;
  for (int i = t; i < CHUNK; i += 256)
    atomicAdd(&h[col[e0 + i] >> 8], 1);
  __syncthreads();
  for (int q = t; q < NBUCK; q += 256) M[blk * NBUCK + q] = h[q];
}

// kp2: per-bucket exclusive scan across chunks: one block per bucket, thread per chunk.
__global__ __launch_bounds__(512) void kp2_rowscan(int* __restrict__ M, int* __restrict__ btot){
  __shared__ int s[512];
  const int b = blockIdx.x, t = threadIdx.x;     // b < NBUCK, t < NBLK
  const int idx = t * NBUCK + b;
  int v = M[idx];
  int x = v;
  s[t] = x; __syncthreads();
  for (int d = 1; d < 512; d <<= 1){
    int y = (t >= d) ? s[t - d] : 0;
    __syncthreads();
    x += y; s[t] = x;
    __syncthreads();
  }
  M[idx] = x - v;                 // exclusive over chunks
  if (t == 511) btot[b] = x;      // bucket total
}

// kp2b: exclusive scan of bucket totals -> bbase[NBUCK+1]
__global__ __launch_bounds__(512) void kp2b_bscan(const int* __restrict__ btot, int* __restrict__ bbase){
  __shared__ int s[512];
  const int t = threadIdx.x;
  int v = (t < NBUCK) ? btot[t] : 0;
  int x = v;
  s[t] = x; __syncthreads();
  for (int d = 1; d < 512; d <<= 1){
    int y = (t >= d) ? s[t - d] : 0;
    __syncthreads();
    x += y; s[t] = x;
    __syncthreads();
  }
  if (t < NBUCK) bbase[t] = x - v;
  if (t == NBUCK - 1) bbase[NBUCK] = x;   // == NE
}

// kp3: coarse scatter, packed (c&255)<<17 | src (src < 2^17). Each (bucket,chunk)
// segment written by exactly one block -> lines single-XCD-owned -> L2 write-merge.
__global__ __launch_bounds__(256) void kp3_scatter(const int* __restrict__ row, const int* __restrict__ col,
                                                   const int* __restrict__ M, const int* __restrict__ bbase,
                                                   unsigned* __restrict__ coarse){
  __shared__ int cur[NBUCK];
  const int blk = blockIdx.x, t = threadIdx.x;
  for (int q = t; q < NBUCK; q += 256) cur[q] = bbase[q] + M[blk * NBUCK + q];
  __syncthreads();
  const int e0 = blk * CHUNK;
  for (int i = t; i < CHUNK; i += 256){
    int c = col[e0 + i];
    int r = row[e0 + i];
    int p = atomicAdd(&cur[c >> 8], 1);            // LDS atomic
    coarse[p] = ((unsigned)(c & 255) << 17) | (unsigned)r;
  }
}

// kp4: one block per bucket: fine sort within block-exclusive csr region; emits
// per-dest start/count/dis.
__global__ __launch_bounds__(256) void kp4_fine(const unsigned* __restrict__ coarse,
                                                const int* __restrict__ bbase,
                                                int* __restrict__ csr,
                                                int* __restrict__ dstart,
                                                int* __restrict__ dcnt,
                                                float* __restrict__ dis){
  __shared__ int cnt[256], ofs[256], rk[256], s[256];
  const int b = blockIdx.x, t = threadIdx.x;
  const int base = bbase[b];
  const int nreg = bbase[b + 1] - base;
  cnt[t] = 0; rk[t] = 0;
  __syncthreads();
  for (int i = t; i < nreg; i += 256)
    atomicAdd(&cnt[coarse[base + i] >> 17], 1);
  __syncthreads();
  const int deg = cnt[t];
  int x = deg;
  s[t] = x; __syncthreads();
  for (int d = 1; d < 256; d <<= 1){
    int y = (t >= d) ? s[t - d] : 0;
    __syncthreads();
    x += y; s[t] = x;
    __syncthreads();
  }
  ofs[t] = x - deg;
  __syncthreads();
  const int n = (b << 8) + t;
  if (n < NN){
    dstart[n] = base + ofs[t];
    dcnt[n]   = deg;
    dis[n]    = rsqrtf((float)(deg + 1));   // +1 self-loop
  }
  for (int i = t; i < nreg; i += 256){
    unsigned p = coarse[base + i];
    int l = p >> 17;
    int r = atomicAdd(&rk[l], 1);           // LDS atomic
    csr[base + ofs[l] + r] = (int)(p & 0x1FFFFu);
  }
}

// ---- h1 = x @ W1, epilogue pre-scales by dis[n]: hs = h1 * dis[n] ----
__global__ __launch_bounds__(256) void k_gemm1(const float* __restrict__ x,
                                               const float* __restrict__ W1,
                                               const float* __restrict__ dis,
                                               float* __restrict__ hs){
  const int lane = threadIdx.x & 63;
  const int wid  = (blockIdx.x * blockDim.x + threadIdx.x) >> 6;
  const int nw   = (gridDim.x * blockDim.x) >> 6;
  const bool s5 = (lane & 32) != 0;
  const bool s4 = (lane & 16) != 0;
  const bool s3 = (lane & 8)  != 0;
  const bool s2 = (lane & 4)  != 0;

  float4 w4[8][4];
  const float4* W1v = (const float4*)W1;
#pragma unroll
  for (int k = 0; k < 8; ++k)
#pragma unroll
    for (int jj = 0; jj < 4; ++jj)
      w4[k][jj] = W1v[(lane * 8 + k) * 4 + jj];

  for (int n = wid; n < NN; n += nw){
    const float4* xp = (const float4*)(x + (size_t)n * DIMK + lane * 8);
    float4 xa = xp[0], xb = xp[1];
    float xv[8] = {xa.x, xa.y, xa.z, xa.w, xb.x, xb.y, xb.z, xb.w};
    float acc[16];
#pragma unroll
    for (int j = 0; j < 16; ++j) acc[j] = 0.f;
#pragma unroll
    for (int k = 0; k < 8; ++k){
      float xk = xv[k];
#pragma unroll
      for (int jj = 0; jj < 4; ++jj){
        acc[jj*4+0] = fmaf(xk, w4[k][jj].x, acc[jj*4+0]);
        acc[jj*4+1] = fmaf(xk, w4[k][jj].y, acc[jj*4+1]);
        acc[jj*4+2] = fmaf(xk, w4[k][jj].z, acc[jj*4+2]);
        acc[jj*4+3] = fmaf(xk, w4[k][jj].w, acc[jj*4+3]);
      }
    }
    float t8[8];
#pragma unroll
    for (int m = 0; m < 8; ++m){
      float keep = s5 ? acc[8+m] : acc[m];
      float give = s5 ? acc[m]   : acc[8+m];
      t8[m] = keep + __shfl_xor(give, 32, 64);
    }
    float t4[4];
#pragma unroll
    for (int m = 0; m < 4; ++m){
      float keep = s4 ? t8[4+m] : t8[m];
      float give = s4 ? t8[m]   : t8[4+m];
      t4[m] = keep + __shfl_xor(give, 16, 64);
    }
    float t2[2];
#pragma unroll
    for (int m = 0; m < 2; ++m){
      float keep = s3 ? t4[2+m] : t4[m];
      float give = s3 ? t4[m]   : t4[2+m];
      t2[m] = keep + __shfl_xor(give, 8, 64);
    }
    float keep = s2 ? t2[1] : t2[0];
    float give = s2 ? t2[0] : t2[1];
    float v = keep + __shfl_xor(give, 4, 64);
    v += __shfl_xor(v, 2, 64);
    v += __shfl_xor(v, 1, 64);
    float hv = __shfl(v, (lane & 15) * 4, 64);
    if (lane < 16) hs[(size_t)n * HIDN + lane] = hv * dis[n];
  }
}

// ---- layer-1 pull aggregation + fin1 fused: wave per node, atomic-free ----
// ILP restructure: one coalesced 64-lane csr load per 64-edge batch, then shfl-
// broadcast indices -> all gathers in a batch are INDEPENDENT (no load->load chain).
__global__ __launch_bounds__(256) void k_agg1(const int* __restrict__ csr,
                                              const int* __restrict__ dstart,
                                              const int* __restrict__ dcnt,
                                              const float* __restrict__ hs,
                                              const float* __restrict__ dis,
                                              const float* __restrict__ b1,
                                              float* __restrict__ h2s){
  const int lane = threadIdx.x & 63;
  const int wid  = (blockIdx.x * blockDim.x + threadIdx.x) >> 6;
  const int nw   = (gridDim.x * blockDim.x) >> 6;
  const int j  = lane & 15;
  const int c4 = lane >> 4;
  for (int n = wid; n < NN; n += nw){
    const int start = dstart[n];
    const int end   = start + dcnt[n];
    float acc = 0.f;
    for (int base = start; base < end; base += 64){
      const int m = min(end - base, 64);            // edges in this batch
      int rv = (lane < m) ? csr[base + lane] : 0;   // one coalesced load
      const int itmax = (m + 3) >> 2;               // wave-uniform bound
      for (int it = 0; it < itmax; ++it){
        int e = it * 4 + c4;
        int r = __shfl(rv, e & 63, 64);             // all lanes active
        if (e < m) acc += hs[r * HIDN + j];         // independent gathers
      }
    }
    acc += __shfl_xor(acc, 16, 64);
    acc += __shfl_xor(acc, 32, 64);
    if (lane < 16){
      float dn = dis[n];
      int t = n * HIDN + lane;
      float v = fmaf(dn, acc + hs[t], b1[lane]);
      v = fmaxf(v, 0.f);
      unsigned bits = threefry_bits((unsigned)t);
      float kept = (bits & 0x80000000u) ? 0.f : v * 2.f;   // /(1-p) = *2
      h2s[t] = kept * dn;                                   // pre-scale for layer 2
    }
  }
}

// ---- layer-2 pull aggregation + W2 matmul + log_softmax fused: wave per node ----
__global__ __launch_bounds__(256) void k_agg2out(const int* __restrict__ csr,
                                                 const int* __restrict__ dstart,
                                                 const int* __restrict__ dcnt,
                                                 const float* __restrict__ h2s,
                                                 const float* __restrict__ dis,
                                                 const float* __restrict__ W2,
                                                 const float* __restrict__ b2,
                                                 float* __restrict__ out){
  const int lane = threadIdx.x & 63;
  const int wid  = (blockIdx.x * blockDim.x + threadIdx.x) >> 6;
  const int nw   = (gridDim.x * blockDim.x) >> 6;
  const int j  = lane & 15;
  const int c4 = lane >> 4;
  float wc[16];
#pragma unroll
  for (int k = 0; k < 16; ++k) wc[k] = W2[k * NCLS + lane];
  const float bb = b2[lane];
  for (int n = wid; n < NN; n += nw){
    const int start = dstart[n];
    const int end   = start + dcnt[n];
    float acc = 0.f;
    for (int base = start; base < end; base += 64){
      const int m = min(end - base, 64);
      int rv = (lane < m) ? csr[base + lane] : 0;
      const int itmax = (m + 3) >> 2;
      for (int it = 0; it < itmax; ++it){
        int e = it * 4 + c4;
        int r = __shfl(rv, e & 63, 64);
        if (e < m) acc += h2s[r * HIDN + j];
      }
    }
    acc += __shfl_xor(acc, 16, 64);
    acc += __shfl_xor(acc, 32, 64);
    float dn = dis[n];
    float aggj = dn * (acc + h2s[n * HIDN + j]);
    float s = bb;
#pragma unroll
    for (int k = 0; k < 16; ++k) s = fmaf(__shfl(aggj, k, 64), wc[k], s);
    float m2 = s;
#pragma unroll
    for (int d = 32; d; d >>= 1) m2 = fmaxf(m2, __shfl_xor(m2, d, 64));
    float ex = __expf(s - m2);
    float sum = ex;
#pragma unroll
    for (int d = 32; d; d >>= 1) sum += __shfl_xor(sum, d, 64);
    out[(size_t)n * NCLS + lane] = (s - m2) - __logf(sum);
  }
}

// ---------------- launch ----------------
extern "C" void kernel_launch(void* const* d_in, const int* in_sizes, int n_in,
                              void* d_out, int out_size, void* d_ws, size_t ws_size,
                              hipStream_t stream){
  const float* x  = (const float*)d_in[0];
  const int*   ei = (const int*)  d_in[1];
  const float* W1 = (const float*)d_in[2];
  const float* b1 = (const float*)d_in[3];
  const float* W2 = (const float*)d_in[4];
  const float* b2 = (const float*)d_in[5];
  float* out = (float*)d_out;
  const int* row = ei;          // sources
  const int* col = ei + NE;     // destinations

  char* ws = (char*)d_ws;
  int*      M      = (int*)     (ws + 0);          // 800,768 B  coarse matrix
  int*      btot   = (int*)     (ws + 800768);     // 1.6 KB
  int*      bbase  = (int*)     (ws + 802368);     // 1.6 KB
  int*      dstart = (int*)     (ws + 803968);     // 400 KB
  int*      dcnt   = (int*)     (ws + 1203968);    // 400 KB
  float*    dis    = (float*)   (ws + 1603968);    // 400 KB
  int*      csr    = (int*)     (ws + 2003968);    // 12.8 MB
  unsigned* coarse = (unsigned*)(ws + 14803968);   // 12.8 MB (dead after kp4)
  float*    hs     = (float*)   (ws + 14803968);   // 6.4 MB  (aliases coarse)
  float*    h2s    = (float*)   (ws + 21203968);   // 6.4 MB  (aliases coarse hi half)

  kp1_hist   <<<NBLK, 256, 0, stream>>>(col, M);
  kp2_rowscan<<<NBUCK, 512, 0, stream>>>(M, btot);
  kp2b_bscan <<<1, 512, 0, stream>>>(btot, bbase);
  kp3_scatter<<<NBLK, 256, 0, stream>>>(row, col, M, bbase, coarse);
  kp4_fine   <<<NBUCK, 256, 0, stream>>>(coarse, bbase, csr, dstart, dcnt, dis);
  k_gemm1    <<<1024, 256, 0, stream>>>(x, W1, dis, hs);
  k_agg1     <<<2048, 256, 0, stream>>>(csr, dstart, dcnt, hs, dis, b1, h2s);
  k_agg2out  <<<2048, 256, 0, stream>>>(csr, dstart, dcnt, h2s, dis, W2, b2, out);
}

// Round 5
// 549.124 us; speedup vs baseline: 1.6322x; 1.0282x over previous
//
#include <hip/hip_runtime.h>

#define NN    100000
#define NE    3200000
#define DIMK  512
#define HIDN  16
#define NCLS  64
#define NBUCK 391        // ceil(NN / 256) coarse buckets (dest >> 8)
#define NBLK  512        // coarse-pass chunks
#define CHUNK 6250       // NE / NBLK exactly

// ---- threefry2x32-20, JAX partitionable 32-bit path: bits = x0_final ^ x1_final,
// key=(0,42), counter=(0, i). Verified (absmax 0.031).
__device__ __forceinline__ unsigned rotl32(unsigned x, int r){ return (x << r) | (x >> (32 - r)); }

__device__ __forceinline__ unsigned threefry_bits(unsigned i){
  const unsigned k0 = 0u, k1 = 42u;
  const unsigned k2 = 0x1BD11BDAu ^ k0 ^ k1;
  unsigned a = 0u + k0, b = i + k1;
#define TF_R(r) { a += b; b = rotl32(b, (r)); b ^= a; }
  TF_R(13) TF_R(15) TF_R(26) TF_R(6)  a += k1; b += k2 + 1u;
  TF_R(17) TF_R(29) TF_R(16) TF_R(24) a += k2; b += k0 + 2u;
  TF_R(13) TF_R(15) TF_R(26) TF_R(6)  a += k0; b += k1 + 3u;
  TF_R(17) TF_R(29) TF_R(16) TF_R(24) a += k1; b += k2 + 4u;
  TF_R(13) TF_R(15) TF_R(26) TF_R(6)  a += k2; b += k0 + 5u;
#undef TF_R
  return a ^ b;   // keep iff !(bits & 0x80000000)
}

// ---------------- CSR build: deterministic two-level counting sort ----------------
// kp1: coarse histogram per chunk -> M[blk*NBUCK + b]  (LDS atomics only)
__global__ __launch_bounds__(256) void kp1_hist(const int* __restrict__ col, int* __restrict__ M){
  __shared__ int h[NBUCK];
  const int blk = blockIdx.x, t = threadIdx.x;
  for (int q = t; q < NBUCK; q += 256) h[q] = 0;
  __syncthreads();
  const int e0 = blk * CHUNK;
  for (int i = t; i < CHUNK; i += 256)
    atomicAdd(&h[col[e0 + i] >> 8], 1);
  __syncthreads();
  for (int q = t; q < NBUCK; q += 256) M[blk * NBUCK + q] = h[q];
}

// kp2: per-bucket exclusive scan across chunks: one block per bucket, thread per chunk.
__global__ __launch_bounds__(512) void kp2_rowscan(int* __restrict__ M, int* __restrict__ btot){
  __shared__ int s[512];
  const int b = blockIdx.x, t = threadIdx.x;     // b < NBUCK, t < NBLK
  const int idx = t * NBUCK + b;
  int v = M[idx];
  int x = v;
  s[t] = x; __syncthreads();
  for (int d = 1; d < 512; d <<= 1){
    int y = (t >= d) ? s[t - d] : 0;
    __syncthreads();
    x += y; s[t] = x;
    __syncthreads();
  }
  M[idx] = x - v;                 // exclusive over chunks
  if (t == 511) btot[b] = x;      // bucket total
}

// kp2b: exclusive scan of bucket totals -> bbase[NBUCK+1]
__global__ __launch_bounds__(512) void kp2b_bscan(const int* __restrict__ btot, int* __restrict__ bbase){
  __shared__ int s[512];
  const int t = threadIdx.x;
  int v = (t < NBUCK) ? btot[t] : 0;
  int x = v;
  s[t] = x; __syncthreads();
  for (int d = 1; d < 512; d <<= 1){
    int y = (t >= d) ? s[t - d] : 0;
    __syncthreads();
    x += y; s[t] = x;
    __syncthreads();
  }
  if (t < NBUCK) bbase[t] = x - v;
  if (t == NBUCK - 1) bbase[NBUCK] = x;   // == NE
}

// kp3: coarse scatter, packed (c&255)<<17 | src (src < 2^17). Each (bucket,chunk)
// segment written by exactly one block -> lines single-XCD-owned -> L2 write-merge.
__global__ __launch_bounds__(256) void kp3_scatter(const int* __restrict__ row, const int* __restrict__ col,
                                                   const int* __restrict__ M, const int* __restrict__ bbase,
                                                   unsigned* __restrict__ coarse){
  __shared__ int cur[NBUCK];
  const int blk = blockIdx.x, t = threadIdx.x;
  for (int q = t; q < NBUCK; q += 256) cur[q] = bbase[q] + M[blk * NBUCK + q];
  __syncthreads();
  const int e0 = blk * CHUNK;
  for (int i = t; i < CHUNK; i += 256){
    int c = col[e0 + i];
    int r = row[e0 + i];
    int p = atomicAdd(&cur[c >> 8], 1);            // LDS atomic
    coarse[p] = ((unsigned)(c & 255) << 17) | (unsigned)r;
  }
}

// kp4: one block per bucket: fine sort within block-exclusive csr region; emits
// per-dest start/count/dis.
__global__ __launch_bounds__(256) void kp4_fine(const unsigned* __restrict__ coarse,
                                                const int* __restrict__ bbase,
                                                int* __restrict__ csr,
                                                int* __restrict__ dstart,
                                                int* __restrict__ dcnt,
                                                float* __restrict__ dis){
  __shared__ int cnt[256], ofs[256], rk[256], s[256];
  const int b = blockIdx.x, t = threadIdx.x;
  const int base = bbase[b];
  const int nreg = bbase[b + 1] - base;
  cnt[t] = 0; rk[t] = 0;
  __syncthreads();
  for (int i = t; i < nreg; i += 256)
    atomicAdd(&cnt[coarse[base + i] >> 17], 1);
  __syncthreads();
  const int deg = cnt[t];
  int x = deg;
  s[t] = x; __syncthreads();
  for (int d = 1; d < 256; d <<= 1){
    int y = (t >= d) ? s[t - d] : 0;
    __syncthreads();
    x += y; s[t] = x;
    __syncthreads();
  }
  ofs[t] = x - deg;
  __syncthreads();
  const int n = (b << 8) + t;
  if (n < NN){
    dstart[n] = base + ofs[t];
    dcnt[n]   = deg;
    dis[n]    = rsqrtf((float)(deg + 1));   // +1 self-loop
  }
  for (int i = t; i < nreg; i += 256){
    unsigned p = coarse[base + i];
    int l = p >> 17;
    int r = atomicAdd(&rk[l], 1);           // LDS atomic
    csr[base + ofs[l] + r] = (int)(p & 0x1FFFFu);
  }
}

// ---- h1 = x @ W1, epilogue pre-scales by dis[n], stores FP16: hs16 = (f16)(h1*dis) ----
// fp16 table = 3.2 MB -> fits every XCD's 4 MB L2 -> agg gathers become L2-resident.
__global__ __launch_bounds__(256) void k_gemm1(const float* __restrict__ x,
                                               const float* __restrict__ W1,
                                               const float* __restrict__ dis,
                                               _Float16* __restrict__ hs16){
  const int lane = threadIdx.x & 63;
  const int wid  = (blockIdx.x * blockDim.x + threadIdx.x) >> 6;
  const int nw   = (gridDim.x * blockDim.x) >> 6;
  const bool s5 = (lane & 32) != 0;
  const bool s4 = (lane & 16) != 0;
  const bool s3 = (lane & 8)  != 0;
  const bool s2 = (lane & 4)  != 0;

  float4 w4[8][4];
  const float4* W1v = (const float4*)W1;
#pragma unroll
  for (int k = 0; k < 8; ++k)
#pragma unroll
    for (int jj = 0; jj < 4; ++jj)
      w4[k][jj] = W1v[(lane * 8 + k) * 4 + jj];

  for (int n = wid; n < NN; n += nw){
    const float4* xp = (const float4*)(x + (size_t)n * DIMK + lane * 8);
    float4 xa = xp[0], xb = xp[1];
    float xv[8] = {xa.x, xa.y, xa.z, xa.w, xb.x, xb.y, xb.z, xb.w};
    float acc[16];
#pragma unroll
    for (int j = 0; j < 16; ++j) acc[j] = 0.f;
#pragma unroll
    for (int k = 0; k < 8; ++k){
      float xk = xv[k];
#pragma unroll
      for (int jj = 0; jj < 4; ++jj){
        acc[jj*4+0] = fmaf(xk, w4[k][jj].x, acc[jj*4+0]);
        acc[jj*4+1] = fmaf(xk, w4[k][jj].y, acc[jj*4+1]);
        acc[jj*4+2] = fmaf(xk, w4[k][jj].z, acc[jj*4+2]);
        acc[jj*4+3] = fmaf(xk, w4[k][jj].w, acc[jj*4+3]);
      }
    }
    float t8[8];
#pragma unroll
    for (int m = 0; m < 8; ++m){
      float keep = s5 ? acc[8+m] : acc[m];
      float give = s5 ? acc[m]   : acc[8+m];
      t8[m] = keep + __shfl_xor(give, 32, 64);
    }
    float t4[4];
#pragma unroll
    for (int m = 0; m < 4; ++m){
      float keep = s4 ? t8[4+m] : t8[m];
      float give = s4 ? t8[m]   : t8[4+m];
      t4[m] = keep + __shfl_xor(give, 16, 64);
    }
    float t2[2];
#pragma unroll
    for (int m = 0; m < 2; ++m){
      float keep = s3 ? t4[2+m] : t4[m];
      float give = s3 ? t4[m]   : t4[2+m];
      t2[m] = keep + __shfl_xor(give, 8, 64);
    }
    float keep = s2 ? t2[1] : t2[0];
    float give = s2 ? t2[0] : t2[1];
    float v = keep + __shfl_xor(give, 4, 64);
    v += __shfl_xor(v, 2, 64);
    v += __shfl_xor(v, 1, 64);
    float hv = __shfl(v, (lane & 15) * 4, 64);
    if (lane < 16) hs16[(size_t)n * HIDN + lane] = (_Float16)(hv * dis[n]);
  }
}

// ---- layer-1 pull aggregation + fin1 fused: wave per node, atomic-free ----
// coalesced 64-lane csr load per batch + shfl-broadcast -> independent fp16 gathers.
__global__ __launch_bounds__(256) void k_agg1(const int* __restrict__ csr,
                                              const int* __restrict__ dstart,
                                              const int* __restrict__ dcnt,
                                              const _Float16* __restrict__ hs16,
                                              const float* __restrict__ dis,
                                              const float* __restrict__ b1,
                                              _Float16* __restrict__ h2s16){
  const int lane = threadIdx.x & 63;
  const int wid  = (blockIdx.x * blockDim.x + threadIdx.x) >> 6;
  const int nw   = (gridDim.x * blockDim.x) >> 6;
  const int j  = lane & 15;
  const int c4 = lane >> 4;
  for (int n = wid; n < NN; n += nw){
    const int start = dstart[n];
    const int end   = start + dcnt[n];
    float acc = 0.f;
    for (int base = start; base < end; base += 64){
      const int m = min(end - base, 64);            // edges in this batch
      int rv = (lane < m) ? csr[base + lane] : 0;   // one coalesced load
      const int itmax = (m + 3) >> 2;               // wave-uniform bound
      for (int it = 0; it < itmax; ++it){
        int e = it * 4 + c4;
        int r = __shfl(rv, e & 63, 64);             // all lanes active
        if (e < m) acc += (float)hs16[r * HIDN + j];  // independent gathers (32B/edge)
      }
    }
    acc += __shfl_xor(acc, 16, 64);
    acc += __shfl_xor(acc, 32, 64);
    if (lane < 16){
      float dn = dis[n];
      int t = n * HIDN + lane;
      float v = fmaf(dn, acc + (float)hs16[t], b1[lane]);
      v = fmaxf(v, 0.f);
      unsigned bits = threefry_bits((unsigned)t);
      float kept = (bits & 0x80000000u) ? 0.f : v * 2.f;   // /(1-p) = *2
      h2s16[t] = (_Float16)(kept * dn);                     // pre-scale for layer 2
    }
  }
}

// ---- layer-2 pull aggregation + W2 matmul + log_softmax fused: wave per node ----
__global__ __launch_bounds__(256) void k_agg2out(const int* __restrict__ csr,
                                                 const int* __restrict__ dstart,
                                                 const int* __restrict__ dcnt,
                                                 const _Float16* __restrict__ h2s16,
                                                 const float* __restrict__ dis,
                                                 const float* __restrict__ W2,
                                                 const float* __restrict__ b2,
                                                 float* __restrict__ out){
  const int lane = threadIdx.x & 63;
  const int wid  = (blockIdx.x * blockDim.x + threadIdx.x) >> 6;
  const int nw   = (gridDim.x * blockDim.x) >> 6;
  const int j  = lane & 15;
  const int c4 = lane >> 4;
  float wc[16];
#pragma unroll
  for (int k = 0; k < 16; ++k) wc[k] = W2[k * NCLS + lane];
  const float bb = b2[lane];
  for (int n = wid; n < NN; n += nw){
    const int start = dstart[n];
    const int end   = start + dcnt[n];
    float acc = 0.f;
    for (int base = start; base < end; base += 64){
      const int m = min(end - base, 64);
      int rv = (lane < m) ? csr[base + lane] : 0;
      const int itmax = (m + 3) >> 2;
      for (int it = 0; it < itmax; ++it){
        int e = it * 4 + c4;
        int r = __shfl(rv, e & 63, 64);
        if (e < m) acc += (float)h2s16[r * HIDN + j];
      }
    }
    acc += __shfl_xor(acc, 16, 64);
    acc += __shfl_xor(acc, 32, 64);
    float dn = dis[n];
    float aggj = dn * (acc + (float)h2s16[n * HIDN + j]);
    float s = bb;
#pragma unroll
    for (int k = 0; k < 16; ++k) s = fmaf(__shfl(aggj, k, 64), wc[k], s);
    float m2 = s;
#pragma unroll
    for (int d = 32; d; d >>= 1) m2 = fmaxf(m2, __shfl_xor(m2, d, 64));
    float ex = __expf(s - m2);
    float sum = ex;
#pragma unroll
    for (int d = 32; d; d >>= 1) sum += __shfl_xor(sum, d, 64);
    out[(size_t)n * NCLS + lane] = (s - m2) - __logf(sum);
  }
}

// ---------------- launch ----------------
extern "C" void kernel_launch(void* const* d_in, const int* in_sizes, int n_in,
                              void* d_out, int out_size, void* d_ws, size_t ws_size,
                              hipStream_t stream){
  const float* x  = (const float*)d_in[0];
  const int*   ei = (const int*)  d_in[1];
  const float* W1 = (const float*)d_in[2];
  const float* b1 = (const float*)d_in[3];
  const float* W2 = (const float*)d_in[4];
  const float* b2 = (const float*)d_in[5];
  float* out = (float*)d_out;
  const int* row = ei;          // sources
  const int* col = ei + NE;     // destinations

  char* ws = (char*)d_ws;
  int*       M      = (int*)      (ws + 0);          // 800,768 B  coarse matrix
  int*       btot   = (int*)      (ws + 800768);     // 1.6 KB
  int*       bbase  = (int*)      (ws + 802368);     // 1.6 KB
  int*       dstart = (int*)      (ws + 803968);     // 400 KB
  int*       dcnt   = (int*)      (ws + 1203968);    // 400 KB
  float*     dis    = (float*)    (ws + 1603968);    // 400 KB
  int*       csr    = (int*)      (ws + 2003968);    // 12.8 MB
  unsigned*  coarse = (unsigned*) (ws + 14803968);   // 12.8 MB (dead after kp4)
  _Float16*  hs16   = (_Float16*) (ws + 14803968);   // 3.2 MB  (aliases coarse lo)
  _Float16*  h2s16  = (_Float16*) (ws + 18003968);   // 3.2 MB  (aliases coarse hi)

  kp1_hist   <<<NBLK, 256, 0, stream>>>(col, M);
  kp2_rowscan<<<NBUCK, 512, 0, stream>>>(M, btot);
  kp2b_bscan <<<1, 512, 0, stream>>>(btot, bbase);
  kp3_scatter<<<NBLK, 256, 0, stream>>>(row, col, M, bbase, coarse);
  kp4_fine   <<<NBUCK, 256, 0, stream>>>(coarse, bbase, csr, dstart, dcnt, dis);
  k_gemm1    <<<1024, 256, 0, stream>>>(x, W1, dis, hs16);
  k_agg1     <<<2048, 256, 0, stream>>>(csr, dstart, dcnt, hs16, dis, b1, h2s16);
  k_agg2out  <<<2048, 256, 0, stream>>>(csr, dstart, dcnt, h2s16, dis, W2, b2, out);
}